// Round 14
// baseline (192.784 us; speedup 1.0000x reference)
//
#include <hip/hip_runtime.h>
#include <math.h>

// CBAM pillar kernel for MI355X (gfx950) — round 14.
//
// R13 (62.7us): conflicts fixed (10M->0.4M), but static grid-stride left
// 24% tail imbalance (6250 groups / 4096 waves -> half the waves idle in
// round 2) and phase-2 metadata loads sat serially after the drain.
// R14: (a) dynamic work-stealing via atomic counter in d_ws, next group
// drawn at trip START (latency hidden under trip body); (b) metadata
// loads hoisted above phase 1.  Structure otherwise identical to R13.

#define CO 64

__device__ __forceinline__ float sgm(float x) {
  return 1.0f / (1.0f + __expf(-x));
}
template <int PAT>
__device__ __forceinline__ float qadd(float s) {
  int t = __builtin_amdgcn_update_dpp(0, __builtin_bit_cast(int, s),
                                      PAT, 0xf, 0xf, true);
  return s + __builtin_bit_cast(float, t);
}
template <int PAT>
__device__ __forceinline__ float qmaxd(float m) {
  int t = __builtin_amdgcn_update_dpp(__builtin_bit_cast(int, m),
                                      __builtin_bit_cast(int, m),
                                      PAT, 0xf, 0xf, false);
  return fmaxf(m, __builtin_bit_cast(float, t));
}
template <int PAT>
__device__ __forceinline__ float qmind(float m) {
  int t = __builtin_amdgcn_update_dpp(__builtin_bit_cast(int, m),
                                      __builtin_bit_cast(int, m),
                                      PAT, 0xf, 0xf, false);
  return fminf(m, __builtin_bit_cast(float, t));
}
// full exchange within each 4-lane quad: 0xB1=[1,0,3,2], 0x4E=[2,3,0,1]
__device__ __forceinline__ float qsum4(float s) { return qadd<0x4E>(qadd<0xB1>(s)); }
__device__ __forceinline__ float qmax4(float m) { return qmaxd<0x4E>(qmaxd<0xB1>(m)); }
__device__ __forceinline__ float qmin4(float m) { return qmind<0x4E>(qmind<0xB1>(m)); }
__device__ __forceinline__ void drain_lds() {
  __builtin_amdgcn_wave_barrier();
  __builtin_amdgcn_s_waitcnt(0xC07F);   // lgkmcnt(0)
  __builtin_amdgcn_wave_barrier();
}

// per-voxel: pvox[2p+slot] = {vf[5], bits(bin), 0, 0}  (32B records)
// thread 0 also initializes the work-queue counter (d_ws is poisoned 0xAA).
__global__ __launch_bounds__(256) void pack_kernel(
    const float* __restrict__ vf, const int* __restrict__ vcoord,
    const int* __restrict__ unq_inv, float* __restrict__ pvox,
    int* __restrict__ counter, int initCount, int n) {
  int i = blockIdx.x * blockDim.x + threadIdx.x;
  if (i == 0) *counter = initCount;
  if (i >= n) return;
  int p = unq_inv[i];
  int slot = (i > 0 && unq_inv[i - 1] == p) ? 1 : 0;
  float* dst = pvox + 8 * (size_t)(2 * p + slot);
#pragma unroll
  for (int k = 0; k < 5; ++k) dst[k] = vf[5 * i + k];
  ((int*)dst)[5] = vcoord[4 * i + 1];
}

__global__ __launch_bounds__(256) void cbam_kernel(
    const float* __restrict__ pvox, const int* __restrict__ unq_cnt,
    const float* __restrict__ W1, const float* __restrict__ b1,
    const float* __restrict__ W2, const float* __restrict__ b2,
    const float* __restrict__ Wc1, const float* __restrict__ bc1,
    const float* __restrict__ Wc2, const float* __restrict__ bc2,
    const float* __restrict__ Wsp, const float* __restrict__ bsp,
    int* __restrict__ counter, float* __restrict__ out,
    int U, int ngroups) {
  __shared__ __align__(16) float w2b[2176];   // 32 rows, stride 68 (pad)
  __shared__ __align__(16) float wc1b[1024];  // k-major: [(4k+q)*16 + j]
  __shared__ __align__(16) float wc2b[1024];  // k-major Wc2^T
  __shared__ __align__(16) float c0b[64], b2b[64], bc2b[64], bc1b[16];
  __shared__ __align__(16) float wsmx[64];    // float2[32] window sums
  __shared__ __align__(16) float wtab[16];    // float2[8] taps, [7]={0,0}
  __shared__ __align__(16) float hbuf[4][1152];  // per-wave 32 x stride 36

  const int tid = threadIdx.x;

  // ---- stage weights to LDS (once per block; persistent blocks)
  for (int i = tid; i < 2048; i += 256) w2b[(i >> 6) * 68 + (i & 63)] = W2[i];
  for (int i = tid; i < 1024; i += 256) {
    // i = ch*16 + j, ch = 16q + k  ->  dst (4k+q)*16 + j
    int ch = i >> 4, j = i & 15, qq = ch >> 4, k = ch & 15;
    wc1b[(4 * k + qq) * 16 + j] = Wc1[i];
    wc2b[(4 * k + qq) * 16 + j] = Wc2[j * 64 + ch];
  }
  if (tid < 64) { b2b[tid] = b2[tid]; bc2b[tid] = bc2[tid]; }
  if (tid < 16) bc1b[tid] = bc1[tid];
  if (tid < 32) {
    float sm = 0.0f, sx = 0.0f;
    for (int k = 0; k < 7; ++k)
      if ((unsigned)(tid + k - 3) < 32u) { sm += Wsp[k]; sx += Wsp[7 + k]; }
    wsmx[2 * tid] = sm; wsmx[2 * tid + 1] = sx;
  }
  if (tid < 8) {
    float a = 0.0f, b = 0.0f;
    if (tid < 7) { a = Wsp[tid]; b = Wsp[7 + tid]; }
    wtab[2 * tid] = a; wtab[2 * tid + 1] = b;
  }
  __syncthreads();
  if (tid < 64) {                      // c0[ch] = b2 + relu(b1) @ W2
    float c = b2b[tid];
    for (int j = 0; j < 32; ++j) c += fmaxf(b1[j], 0.0f) * w2b[j * 68 + tid];
    c0b[tid] = c;
  }
  __syncthreads();

  const int wv = tid >> 6, lane = tid & 63;
  float* const hb = hbuf[wv];

  // phase-1 constants (persist across trips)
  const int j32 = lane & 31, vh = lane >> 5;
  float w1r[5];
#pragma unroll
  for (int i = 0; i < 5; ++i) w1r[i] = W1[i * 32 + j32];
  const float b1r = b1[j32];

  const int q = lane & 3, pp = lane >> 2;

  int grp = blockIdx.x * 4 + wv;       // first group: static assignment
  while (grp < ngroups) {
    // ---- draw NEXT group now; atomic latency hides under this trip
    int gn;
    if (lane == 0) gn = atomicAdd(counter, 1);
    gn = __shfl(gn, 0);

    const int P0 = grp * 16;           // 16 pillars this trip

    // ---- phase-2 metadata loads hoisted (latency overlaps phase 1)
    const int pg = P0 + pp;
    const int pc = pg < U ? pg : (U - 1);
    const int cnt = unq_cnt[pc];
    const int* pvi = (const int*)pvox;
    const int b0 = pvi[(size_t)(2 * pc) * 8 + 5] & 31;
    const int b1raw = pvi[(size_t)(2 * pc + 1) * 8 + 5];

    // ---- phase 1: layer1.  lane = (j32, voxel-half vh)
    {
      const float4* pv4 = (const float4*)pvox;
      const int vmax = 2 * U - 1;
#pragma unroll
      for (int v = 0; v < 16; ++v) {
        int vg = 2 * P0 + 16 * vh + v;
        vg = vg < vmax ? vg : vmax;
        float4 g1 = pv4[2 * vg];
        float4 g2 = pv4[2 * vg + 1];
        float h = b1r + g1.x * w1r[0] + g1.y * w1r[1] + g1.z * w1r[2] +
                  g1.w * w1r[3] + g2.x * w1r[4];
        // row = slot*16 + pillar-in-wave  (bank step 4 for phase-2 reads)
        const int row = (v & 1) * 16 + 8 * vh + (v >> 1);
        hb[row * 36 + j32] = fmaxf(h, 0.0f);
      }
    }
    drain_lds();

    // ---- phase 2: lane = (pillar pp, ch-quad q); channels 16q..16q+15
    const bool has2 = (cnt >= 2);
    const int b1e = has2 ? (b1raw & 31) : 64;

    // layer2
    float y0[16], y1[16];
    const float4* b2b4 = (const float4*)b2b;
#pragma unroll
    for (int kb = 0; kb < 4; ++kb) {
      float4 w = b2b4[q * 4 + kb];
      y0[4 * kb] = w.x; y0[4 * kb + 1] = w.y; y0[4 * kb + 2] = w.z; y0[4 * kb + 3] = w.w;
      y1[4 * kb] = w.x; y1[4 * kb + 1] = w.y; y1[4 * kb + 2] = w.z; y1[4 * kb + 3] = w.w;
    }
    const float4* hb4 = (const float4*)hb;
    const float4* w2b4 = (const float4*)w2b;
    // 2-deep read-ahead on h (rows pp and 16+pp, stride 36 floats = 9 f4)
    float4 h0c = hb4[pp * 9];
    float4 h1c = hb4[(16 + pp) * 9];
#pragma unroll
    for (int jb = 0; jb < 8; ++jb) {
      float4 h0n, h1n;
      if (jb < 7) {
        h0n = hb4[pp * 9 + jb + 1];
        h1n = hb4[(16 + pp) * 9 + jb + 1];
      }
      float h0a[4] = {h0c.x, h0c.y, h0c.z, h0c.w};
      float h1a[4] = {h1c.x, h1c.y, h1c.z, h1c.w};
#pragma unroll
      for (int jj = 0; jj < 4; ++jj) {
        const int j = 4 * jb + jj;
#pragma unroll
        for (int kb = 0; kb < 4; ++kb) {
          float4 w = w2b4[17 * j + 4 * q + kb];
          y0[4 * kb]     += h0a[jj] * w.x; y0[4 * kb + 1] += h0a[jj] * w.y;
          y0[4 * kb + 2] += h0a[jj] * w.z; y0[4 * kb + 3] += h0a[jj] * w.w;
          y1[4 * kb]     += h1a[jj] * w.x; y1[4 * kb + 1] += h1a[jj] * w.y;
          y1[4 * kb + 2] += h1a[jj] * w.z; y1[4 * kb + 3] += h1a[jj] * w.w;
        }
      }
      h0c = h0n; h1c = h1n;
    }
#pragma unroll
    for (int k = 0; k < 16; ++k) y1[k] = has2 ? y1[k] : y0[k];

    // pooled stats + chMLP layer1 partials (thread-local over 16 ch)
    float ha[16] = {0}, hm[16] = {0};
    const float kf = has2 ? 30.0f : 31.0f;     // 32 - nocc
    const float inv32 = 1.0f / 32.0f;
    const float4* c04 = (const float4*)c0b;
    const float4* wc14 = (const float4*)wc1b;
#pragma unroll
    for (int kb = 0; kb < 4; ++kb) {
      float4 cq = c04[q * 4 + kb];
      float c0a[4] = {cq.x, cq.y, cq.z, cq.w};
#pragma unroll
      for (int i = 0; i < 4; ++i) {
        const int k = 4 * kb + i;
        const float c0v = c0a[i];
        const float sumy = y0[k] + (has2 ? y1[k] : 0.0f);
        const float avg = fmaf(c0v, kf, sumy) * inv32;
        const float mxv = fmaxf(fmaxf(y0[k], y1[k]), c0v);
#pragma unroll
        for (int jb = 0; jb < 4; ++jb) {
          float4 w = wc14[(4 * k + q) * 4 + jb];   // k-major: q 2-way, free
          ha[4 * jb]     += avg * w.x; ha[4 * jb + 1] += avg * w.y;
          ha[4 * jb + 2] += avg * w.z; ha[4 * jb + 3] += avg * w.w;
          hm[4 * jb]     += mxv * w.x; hm[4 * jb + 1] += mxv * w.y;
          hm[4 * jb + 2] += mxv * w.z; hm[4 * jb + 3] += mxv * w.w;
        }
      }
    }
    // quad-reduce partials, bias, relu, combine pools
    float g[16];
    const float4* bc14 = (const float4*)bc1b;
#pragma unroll
    for (int jb = 0; jb < 4; ++jb) {
      float4 bb = bc14[jb];
      float bba[4] = {bb.x, bb.y, bb.z, bb.w};
#pragma unroll
      for (int i = 0; i < 4; ++i) {
        const int j = 4 * jb + i;
        const float sa = qsum4(ha[j]) + bba[i];
        const float sm = qsum4(hm[j]) + bba[i];
        g[j] = fmaxf(sa, 0.0f) + fmaxf(sm, 0.0f);
      }
    }

    // chMLP layer2 -> attc; bin-column partial reductions
    float attc[16];
    float sc = 0.0f, mc = -3.0e38f;
    float sy0 = 0.0f, my0 = -3.0e38f, sy1 = 0.0f, my1 = -3.0e38f;
    const float4* wc24 = (const float4*)wc2b;
    const float4* bc24 = (const float4*)bc2b;
#pragma unroll
    for (int kb = 0; kb < 4; ++kb) {
      float4 cq = c04[q * 4 + kb];
      float4 bq = bc24[q * 4 + kb];
      float c0a[4] = {cq.x, cq.y, cq.z, cq.w};
      float b2a[4] = {bq.x, bq.y, bq.z, bq.w};
#pragma unroll
      for (int i = 0; i < 4; ++i) {
        const int k = 4 * kb + i;
        float pre = 2.0f * b2a[i];
#pragma unroll
        for (int jb = 0; jb < 4; ++jb) {
          float4 w = wc24[(4 * k + q) * 4 + jb];
          pre += g[4 * jb] * w.x + g[4 * jb + 1] * w.y +
                 g[4 * jb + 2] * w.z + g[4 * jb + 3] * w.w;
        }
        const float a = sgm(pre);
        attc[k] = a;
        const float pc0 = a * c0a[i], py0 = a * y0[k], py1 = a * y1[k];
        sc += pc0;  mc = fmaxf(mc, pc0);
        sy0 += py0; my0 = fmaxf(my0, py0);
        sy1 += py1; my1 = fmaxf(my1, py1);
      }
    }
    sc = qsum4(sc);   mc = qmax4(mc);
    sy0 = qsum4(sy0); my0 = qmax4(my0);
    sy1 = qsum4(sy1); my1 = qmax4(my1);

    // analytic conv over 32 bins, 8 bins per lane, quad-combined
    const float inv64 = 1.0f / 64.0f;
    const float Mn = sc * inv64, Mx = mc;
    const float dm0 = (sy0 - sc) * inv64, dx0 = my0 - mc;
    const float dm1 = (sy1 - sc) * inv64, dx1 = my1 - mc;
    const float bspr = bsp[0];
    const float2* ws2 = (const float2*)wsmx;
    const float2* wt2 = (const float2*)wtab;
    float maxE = -3.0e38f, minE = 3.0e38f, sv0 = -3.0e38f, sv1 = -3.0e38f;
#pragma unroll
    for (int k = 0; k < 8; ++k) {
      const int b = 8 * q + k;
      float2 ws = ws2[b];
      float acc = bspr + Mn * ws.x + Mx * ws.y;
      int k0 = b0 - b + 3;  k0 = ((unsigned)k0 <= 6u) ? k0 : 7;
      int k1 = b1e - b + 3; k1 = ((unsigned)k1 <= 6u) ? k1 : 7;
      float2 w0 = wt2[k0];
      float2 w1v = wt2[k1];
      acc += dm0 * w0.x + dx0 * w0.y + dm1 * w1v.x + dx1 * w1v.y;
      const bool o0 = (b == b0), o1 = (b == b1e);
      const bool oc = o0 || o1;
      maxE = fmaxf(maxE, oc ? -3.0e38f : acc);
      minE = fminf(minE, oc ?  3.0e38f : acc);
      sv0 = o0 ? acc : sv0;
      sv1 = o1 ? acc : sv1;
    }
    maxE = qmax4(maxE); minE = qmin4(minE);
    sv0 = qmax4(sv0);   sv1 = qmax4(sv1);
    const float sig0 = sgm(sv0);
    const float sig1 = has2 ? sgm(sv1) : sig0;
    const float sE = sgm(maxE), sI = sgm(minE);

    // epilogue: final max over bins, stores
    if (pg < U) {
      float4* ov = (float4*)(out + (size_t)pg * CO + 16 * q);
#pragma unroll
      for (int kb = 0; kb < 4; ++kb) {
        float4 cq = c04[q * 4 + kb];
        float c0a[4] = {cq.x, cq.y, cq.z, cq.w};
        float rr[4];
#pragma unroll
        for (int i = 0; i < 4; ++i) {
          const int k = 4 * kb + i;
          const float c0v = c0a[i];
          const float sel = (c0v >= 0.0f) ? sE : sI;
          const float m = fmaxf(fmaxf(y0[k] * sig0, y1[k] * sig1), c0v * sel);
          rr[i] = attc[k] * m;
        }
        float4 r; r.x = rr[0]; r.y = rr[1]; r.z = rr[2]; r.w = rr[3];
        ov[kb] = r;
      }
      if (q == 0) out[(size_t)U * CO + pg] = has2 ? 1.0f : 0.0f;
    }
    drain_lds();   // hbuf reused next trip: all reads done before rewrite
    grp = gn;
  }
}

extern "C" void kernel_launch(void* const* d_in, const int* in_sizes, int n_in,
                              void* d_out, int out_size, void* d_ws, size_t ws_size,
                              hipStream_t stream) {
  const float* vf      = (const float*)d_in[0];
  const int*   vcoord  = (const int*)d_in[1];
  // d_in[2] = unq_coords (unused: identity)
  const int*   unq_inv = (const int*)d_in[3];
  const int*   unq_cnt = (const int*)d_in[4];
  const float* W1  = (const float*)d_in[5];
  const float* b1  = (const float*)d_in[6];
  const float* W2  = (const float*)d_in[7];
  const float* b2  = (const float*)d_in[8];
  const float* Wc1 = (const float*)d_in[9];
  const float* bc1 = (const float*)d_in[10];
  const float* Wc2 = (const float*)d_in[11];
  const float* bc2 = (const float*)d_in[12];
  const float* Wsp = (const float*)d_in[13];
  const float* bsp = (const float*)d_in[14];

  const int N = in_sizes[3];   // voxels
  const int U = in_sizes[4];   // pillars

  float* pvox = (float*)d_ws;              // 2U records x 32B
  int* counter = (int*)(pvox + 16 * (size_t)U);

  const int ngroups = (U + 15) / 16;       // 16 pillars per wave-trip
  int blocks = 1024;                       // 4 blocks/CU resident
  const int maxBlocks = (ngroups + 3) / 4;
  if (blocks > maxBlocks) blocks = maxBlocks;
  const int totalWaves = blocks * 4;

  pack_kernel<<<(N + 255) / 256, 256, 0, stream>>>(
      vf, vcoord, unq_inv, pvox, counter, totalWaves, N);

  cbam_kernel<<<blocks, 256, 0, stream>>>(
      pvox, unq_cnt, W1, b1, W2, b2, Wc1, bc1, Wc2, bc2, Wsp, bsp,
      counter, (float*)d_out, U, ngroups);
}

// Round 15
// 146.179 us; speedup vs baseline: 1.3188x; 1.3188x over previous
//
#include <hip/hip_runtime.h>
#include <math.h>

// CBAM pillar kernel for MI355X (gfx950) — round 15.
//
// R14's atomic work-steal regressed (shfl right after atomicAdd exposed the
// full atomic latency at trip start; VALUBusy 56->34).  R15 = R13 static
// schedule + coalesced 1-trip-ahead voxel prefetch: the 16-pillar block is
// exactly 64 lanes x float4 -> ONE coalesced global load per trip into a
// register, ds_write to per-wave vbuf at trip end, phase 1 reads voxels
// from LDS (uniform-per-half -> broadcast).  Steady-state trips have ~no
// exposed global latency.  Bins read from vbuf; unq_cnt hoisted.

#define CO 64

__device__ __forceinline__ float sgm(float x) {
  return 1.0f / (1.0f + __expf(-x));
}
template <int PAT>
__device__ __forceinline__ float qadd(float s) {
  int t = __builtin_amdgcn_update_dpp(0, __builtin_bit_cast(int, s),
                                      PAT, 0xf, 0xf, true);
  return s + __builtin_bit_cast(float, t);
}
template <int PAT>
__device__ __forceinline__ float qmaxd(float m) {
  int t = __builtin_amdgcn_update_dpp(__builtin_bit_cast(int, m),
                                      __builtin_bit_cast(int, m),
                                      PAT, 0xf, 0xf, false);
  return fmaxf(m, __builtin_bit_cast(float, t));
}
template <int PAT>
__device__ __forceinline__ float qmind(float m) {
  int t = __builtin_amdgcn_update_dpp(__builtin_bit_cast(int, m),
                                      __builtin_bit_cast(int, m),
                                      PAT, 0xf, 0xf, false);
  return fminf(m, __builtin_bit_cast(float, t));
}
// full exchange within each 4-lane quad: 0xB1=[1,0,3,2], 0x4E=[2,3,0,1]
__device__ __forceinline__ float qsum4(float s) { return qadd<0x4E>(qadd<0xB1>(s)); }
__device__ __forceinline__ float qmax4(float m) { return qmaxd<0x4E>(qmaxd<0xB1>(m)); }
__device__ __forceinline__ float qmin4(float m) { return qmind<0x4E>(qmind<0xB1>(m)); }
__device__ __forceinline__ void drain_lds() {
  __builtin_amdgcn_wave_barrier();
  __builtin_amdgcn_s_waitcnt(0xC07F);   // lgkmcnt(0)
  __builtin_amdgcn_wave_barrier();
}

// per-voxel: pvox[2p+slot] = {vf[5], bits(bin), 0, 0}  (32B records)
__global__ __launch_bounds__(256) void pack_kernel(
    const float* __restrict__ vf, const int* __restrict__ vcoord,
    const int* __restrict__ unq_inv, float* __restrict__ pvox, int n) {
  int i = blockIdx.x * blockDim.x + threadIdx.x;
  if (i >= n) return;
  int p = unq_inv[i];
  int slot = (i > 0 && unq_inv[i - 1] == p) ? 1 : 0;
  float* dst = pvox + 8 * (size_t)(2 * p + slot);
#pragma unroll
  for (int k = 0; k < 5; ++k) dst[k] = vf[5 * i + k];
  ((int*)dst)[5] = vcoord[4 * i + 1];
}

__global__ __launch_bounds__(256) void cbam_kernel(
    const float* __restrict__ pvox, const int* __restrict__ unq_cnt,
    const float* __restrict__ W1, const float* __restrict__ b1,
    const float* __restrict__ W2, const float* __restrict__ b2,
    const float* __restrict__ Wc1, const float* __restrict__ bc1,
    const float* __restrict__ Wc2, const float* __restrict__ bc2,
    const float* __restrict__ Wsp, const float* __restrict__ bsp,
    float* __restrict__ out, int U, int ngroups, int totalWaves) {
  __shared__ __align__(16) float w2b[2048];   // 32 x 64 (stride 64)
  __shared__ __align__(16) float wc1b[1024];  // k-major: [(4k+q)*16 + j]
  __shared__ __align__(16) float wc2b[1024];  // k-major Wc2^T
  __shared__ __align__(16) float c0b[64], b2b[64], bc2b[64], bc1b[16];
  __shared__ __align__(16) float wsmx[64];    // float2[32] window sums
  __shared__ __align__(16) float wtab[16];    // float2[8] taps, [7]={0,0}
  __shared__ __align__(16) float hbuf[4][1152];  // per-wave 32 x stride 36
  __shared__ __align__(16) float vbuf[4][256];   // per-wave voxel block (1KB)

  const int tid = threadIdx.x;

  // ---- stage weights to LDS (once per block; persistent blocks)
  for (int i = tid; i < 2048; i += 256) w2b[i] = W2[i];
  for (int i = tid; i < 1024; i += 256) {
    // i = ch*16 + j, ch = 16q + k  ->  dst (4k+q)*16 + j
    int ch = i >> 4, j = i & 15, qq = ch >> 4, k = ch & 15;
    wc1b[(4 * k + qq) * 16 + j] = Wc1[i];
    wc2b[(4 * k + qq) * 16 + j] = Wc2[j * 64 + ch];
  }
  if (tid < 64) { b2b[tid] = b2[tid]; bc2b[tid] = bc2[tid]; }
  if (tid < 16) bc1b[tid] = bc1[tid];
  if (tid < 32) {
    float sm = 0.0f, sx = 0.0f;
    for (int k = 0; k < 7; ++k)
      if ((unsigned)(tid + k - 3) < 32u) { sm += Wsp[k]; sx += Wsp[7 + k]; }
    wsmx[2 * tid] = sm; wsmx[2 * tid + 1] = sx;
  }
  if (tid < 8) {
    float a = 0.0f, b = 0.0f;
    if (tid < 7) { a = Wsp[tid]; b = Wsp[7 + tid]; }
    wtab[2 * tid] = a; wtab[2 * tid + 1] = b;
  }
  __syncthreads();
  if (tid < 64) {                      // c0[ch] = b2 + relu(b1) @ W2
    float c = b2b[tid];
    for (int j = 0; j < 32; ++j) c += fmaxf(b1[j], 0.0f) * w2b[j * 64 + tid];
    c0b[tid] = c;
  }
  __syncthreads();

  const int wv = tid >> 6, lane = tid & 63;
  float* const hb = hbuf[wv];
  float* const vb = vbuf[wv];
  float4* const vb4 = (float4*)vb;

  // phase-1 constants (persist across trips)
  const int j32 = lane & 31, vh = lane >> 5;
  float w1r[5];
#pragma unroll
  for (int i = 0; i < 5; ++i) w1r[i] = W1[i * 32 + j32];
  const float b1r = b1[j32];

  const int q = lane & 3, pp = lane >> 2;
  const float4* pv4 = (const float4*)pvox;
  const int f4max = 4 * U - 1;         // pvox has 4U float4 entries

  // ---- prologue: stage trip-0 voxel block (coalesced 1KB load)
  {
    int idx = 64 * (blockIdx.x * 4 + wv) + lane;
    idx = idx < f4max ? idx : f4max;
    vb4[lane] = pv4[idx];
  }
  drain_lds();

  for (int grp = blockIdx.x * 4 + wv; grp < ngroups; grp += totalWaves) {
    const int P0 = grp * 16;           // 16 pillars this trip

    // ---- prefetch NEXT trip's voxel block (one coalesced load; lands
    // any time before the vb4 write at trip end)
    int nidx = 64 * (grp + totalWaves) + lane;
    nidx = nidx < f4max ? nidx : f4max;
    const float4 pfn = pv4[nidx];

    // ---- metadata (cnt global; bins from current vbuf) hoisted
    const int pg = P0 + pp;
    const int pc = pg < U ? pg : (U - 1);
    const int cnt = unq_cnt[pc];
    const int* vbi = (const int*)vb;
    const int b0 = vbi[(2 * pp) * 8 + 5] & 31;
    const int b1raw = vbi[(2 * pp + 1) * 8 + 5];

    // ---- phase 1: layer1 from vbuf.  lane = (j32, voxel-half vh)
    {
      const float4* vb4c = (const float4*)vb;
#pragma unroll
      for (int v = 0; v < 16; ++v) {
        const int rec = 16 * vh + v;
        float4 g1 = vb4c[2 * rec];       // uniform per half -> broadcast
        float4 g2 = vb4c[2 * rec + 1];
        float h = b1r + g1.x * w1r[0] + g1.y * w1r[1] + g1.z * w1r[2] +
                  g1.w * w1r[3] + g2.x * w1r[4];
        const int row = (v & 1) * 16 + 8 * vh + (v >> 1);
        hb[row * 36 + j32] = fmaxf(h, 0.0f);
      }
    }
    drain_lds();

    // ---- phase 2: lane = (pillar pp, ch-quad q); channels 16q..16q+15
    const bool has2 = (cnt >= 2);
    const int b1e = has2 ? (b1raw & 31) : 64;

    // layer2
    float y0[16], y1[16];
    const float4* b2b4 = (const float4*)b2b;
#pragma unroll
    for (int kb = 0; kb < 4; ++kb) {
      float4 w = b2b4[q * 4 + kb];
      y0[4 * kb] = w.x; y0[4 * kb + 1] = w.y; y0[4 * kb + 2] = w.z; y0[4 * kb + 3] = w.w;
      y1[4 * kb] = w.x; y1[4 * kb + 1] = w.y; y1[4 * kb + 2] = w.z; y1[4 * kb + 3] = w.w;
    }
    const float4* hb4 = (const float4*)hb;
    const float4* w2b4 = (const float4*)w2b;
    float4 h0c = hb4[pp * 9];
    float4 h1c = hb4[(16 + pp) * 9];
#pragma unroll
    for (int jb = 0; jb < 8; ++jb) {
      float4 h0n, h1n;
      if (jb < 7) {
        h0n = hb4[pp * 9 + jb + 1];
        h1n = hb4[(16 + pp) * 9 + jb + 1];
      }
      float h0a[4] = {h0c.x, h0c.y, h0c.z, h0c.w};
      float h1a[4] = {h1c.x, h1c.y, h1c.z, h1c.w};
#pragma unroll
      for (int jj = 0; jj < 4; ++jj) {
        const int j = 4 * jb + jj;
#pragma unroll
        for (int kb = 0; kb < 4; ++kb) {
          float4 w = w2b4[16 * j + 4 * q + kb];  // q 2-way banks: free
          y0[4 * kb]     += h0a[jj] * w.x; y0[4 * kb + 1] += h0a[jj] * w.y;
          y0[4 * kb + 2] += h0a[jj] * w.z; y0[4 * kb + 3] += h0a[jj] * w.w;
          y1[4 * kb]     += h1a[jj] * w.x; y1[4 * kb + 1] += h1a[jj] * w.y;
          y1[4 * kb + 2] += h1a[jj] * w.z; y1[4 * kb + 3] += h1a[jj] * w.w;
        }
      }
      h0c = h0n; h1c = h1n;
    }
#pragma unroll
    for (int k = 0; k < 16; ++k) y1[k] = has2 ? y1[k] : y0[k];

    // pooled stats + chMLP layer1 partials (thread-local over 16 ch)
    float ha[16] = {0}, hm[16] = {0};
    const float kf = has2 ? 30.0f : 31.0f;     // 32 - nocc
    const float inv32 = 1.0f / 32.0f;
    const float4* c04 = (const float4*)c0b;
    const float4* wc14 = (const float4*)wc1b;
#pragma unroll
    for (int kb = 0; kb < 4; ++kb) {
      float4 cq = c04[q * 4 + kb];
      float c0a[4] = {cq.x, cq.y, cq.z, cq.w};
#pragma unroll
      for (int i = 0; i < 4; ++i) {
        const int k = 4 * kb + i;
        const float c0v = c0a[i];
        const float sumy = y0[k] + (has2 ? y1[k] : 0.0f);
        const float avg = fmaf(c0v, kf, sumy) * inv32;
        const float mxv = fmaxf(fmaxf(y0[k], y1[k]), c0v);
#pragma unroll
        for (int jb = 0; jb < 4; ++jb) {
          float4 w = wc14[(4 * k + q) * 4 + jb];   // k-major: q 2-way, free
          ha[4 * jb]     += avg * w.x; ha[4 * jb + 1] += avg * w.y;
          ha[4 * jb + 2] += avg * w.z; ha[4 * jb + 3] += avg * w.w;
          hm[4 * jb]     += mxv * w.x; hm[4 * jb + 1] += mxv * w.y;
          hm[4 * jb + 2] += mxv * w.z; hm[4 * jb + 3] += mxv * w.w;
        }
      }
    }
    // quad-reduce partials, bias, relu, combine pools
    float g[16];
    const float4* bc14 = (const float4*)bc1b;
#pragma unroll
    for (int jb = 0; jb < 4; ++jb) {
      float4 bb = bc14[jb];
      float bba[4] = {bb.x, bb.y, bb.z, bb.w};
#pragma unroll
      for (int i = 0; i < 4; ++i) {
        const int j = 4 * jb + i;
        const float sa = qsum4(ha[j]) + bba[i];
        const float sm = qsum4(hm[j]) + bba[i];
        g[j] = fmaxf(sa, 0.0f) + fmaxf(sm, 0.0f);
      }
    }

    // chMLP layer2 -> attc; bin-column partial reductions
    float attc[16];
    float sc = 0.0f, mc = -3.0e38f;
    float sy0 = 0.0f, my0 = -3.0e38f, sy1 = 0.0f, my1 = -3.0e38f;
    const float4* wc24 = (const float4*)wc2b;
    const float4* bc24 = (const float4*)bc2b;
#pragma unroll
    for (int kb = 0; kb < 4; ++kb) {
      float4 cq = c04[q * 4 + kb];
      float4 bq = bc24[q * 4 + kb];
      float c0a[4] = {cq.x, cq.y, cq.z, cq.w};
      float b2a[4] = {bq.x, bq.y, bq.z, bq.w};
#pragma unroll
      for (int i = 0; i < 4; ++i) {
        const int k = 4 * kb + i;
        float pre = 2.0f * b2a[i];
#pragma unroll
        for (int jb = 0; jb < 4; ++jb) {
          float4 w = wc24[(4 * k + q) * 4 + jb];
          pre += g[4 * jb] * w.x + g[4 * jb + 1] * w.y +
                 g[4 * jb + 2] * w.z + g[4 * jb + 3] * w.w;
        }
        const float a = sgm(pre);
        attc[k] = a;
        const float pc0 = a * c0a[i], py0 = a * y0[k], py1 = a * y1[k];
        sc += pc0;  mc = fmaxf(mc, pc0);
        sy0 += py0; my0 = fmaxf(my0, py0);
        sy1 += py1; my1 = fmaxf(my1, py1);
      }
    }
    sc = qsum4(sc);   mc = qmax4(mc);
    sy0 = qsum4(sy0); my0 = qmax4(my0);
    sy1 = qsum4(sy1); my1 = qmax4(my1);

    // analytic conv over 32 bins, 8 bins per lane, quad-combined
    const float inv64 = 1.0f / 64.0f;
    const float Mn = sc * inv64, Mx = mc;
    const float dm0 = (sy0 - sc) * inv64, dx0 = my0 - mc;
    const float dm1 = (sy1 - sc) * inv64, dx1 = my1 - mc;
    const float bspr = bsp[0];
    const float2* ws2 = (const float2*)wsmx;
    const float2* wt2 = (const float2*)wtab;
    float maxE = -3.0e38f, minE = 3.0e38f, sv0 = -3.0e38f, sv1 = -3.0e38f;
#pragma unroll
    for (int k = 0; k < 8; ++k) {
      const int b = 8 * q + k;
      float2 ws = ws2[b];
      float acc = bspr + Mn * ws.x + Mx * ws.y;
      int k0 = b0 - b + 3;  k0 = ((unsigned)k0 <= 6u) ? k0 : 7;
      int k1 = b1e - b + 3; k1 = ((unsigned)k1 <= 6u) ? k1 : 7;
      float2 w0 = wt2[k0];
      float2 w1v = wt2[k1];
      acc += dm0 * w0.x + dx0 * w0.y + dm1 * w1v.x + dx1 * w1v.y;
      const bool o0 = (b == b0), o1 = (b == b1e);
      const bool oc = o0 || o1;
      maxE = fmaxf(maxE, oc ? -3.0e38f : acc);
      minE = fminf(minE, oc ?  3.0e38f : acc);
      sv0 = o0 ? acc : sv0;
      sv1 = o1 ? acc : sv1;
    }
    maxE = qmax4(maxE); minE = qmin4(minE);
    sv0 = qmax4(sv0);   sv1 = qmax4(sv1);
    const float sig0 = sgm(sv0);
    const float sig1 = has2 ? sgm(sv1) : sig0;
    const float sE = sgm(maxE), sI = sgm(minE);

    // epilogue: final max over bins, stores
    if (pg < U) {
      float4* ov = (float4*)(out + (size_t)pg * CO + 16 * q);
#pragma unroll
      for (int kb = 0; kb < 4; ++kb) {
        float4 cq = c04[q * 4 + kb];
        float c0a[4] = {cq.x, cq.y, cq.z, cq.w};
        float rr[4];
#pragma unroll
        for (int i = 0; i < 4; ++i) {
          const int k = 4 * kb + i;
          const float c0v = c0a[i];
          const float sel = (c0v >= 0.0f) ? sE : sI;
          const float m = fmaxf(fmaxf(y0[k] * sig0, y1[k] * sig1), c0v * sel);
          rr[i] = attc[k] * m;
        }
        float4 r; r.x = rr[0]; r.y = rr[1]; r.z = rr[2]; r.w = rr[3];
        ov[kb] = r;
      }
      if (q == 0) out[(size_t)U * CO + pg] = has2 ? 1.0f : 0.0f;
    }

    // ---- rotate: stage next trip's voxel block (reads retired at drain1)
    vb4[lane] = pfn;
    drain_lds();   // covers vbuf write + hbuf reuse next trip
  }
}

extern "C" void kernel_launch(void* const* d_in, const int* in_sizes, int n_in,
                              void* d_out, int out_size, void* d_ws, size_t ws_size,
                              hipStream_t stream) {
  const float* vf      = (const float*)d_in[0];
  const int*   vcoord  = (const int*)d_in[1];
  // d_in[2] = unq_coords (unused: identity)
  const int*   unq_inv = (const int*)d_in[3];
  const int*   unq_cnt = (const int*)d_in[4];
  const float* W1  = (const float*)d_in[5];
  const float* b1  = (const float*)d_in[6];
  const float* W2  = (const float*)d_in[7];
  const float* b2  = (const float*)d_in[8];
  const float* Wc1 = (const float*)d_in[9];
  const float* bc1 = (const float*)d_in[10];
  const float* Wc2 = (const float*)d_in[11];
  const float* bc2 = (const float*)d_in[12];
  const float* Wsp = (const float*)d_in[13];
  const float* bsp = (const float*)d_in[14];

  const int N = in_sizes[3];   // voxels
  const int U = in_sizes[4];   // pillars

  float* pvox = (float*)d_ws;  // 2U records x 32B (6.4 MB @ U=100k)

  pack_kernel<<<(N + 255) / 256, 256, 0, stream>>>(vf, vcoord, unq_inv, pvox, N);

  const int ngroups = (U + 15) / 16;      // 16 pillars per wave-trip
  int blocks = 1024;                      // 4 blocks/CU resident
  const int maxBlocks = (ngroups + 3) / 4;
  if (blocks > maxBlocks) blocks = maxBlocks;
  const int totalWaves = blocks * 4;
  cbam_kernel<<<blocks, 256, 0, stream>>>(
      pvox, unq_cnt, W1, b1, W2, b2, Wc1, bc1, Wc2, bc2, Wsp, bsp,
      (float*)d_out, U, ngroups, totalWaves);
}